// Round 1
// baseline (1522.067 us; speedup 1.0000x reference)
//
#include <hip/hip_runtime.h>
#include <hip/hip_bf16.h>

#define BATCH 256
#define TSTEPS 4096
#define HID 136
#define HPAD 144      // padded hidden for aligned 4-way k-split (4 x 36)
#define ODIM 68
#define KR 36         // k-chunk length per ks lane

__device__ __forceinline__ float fast_tanh(float z) {
    float az = fabsf(z);
    float e = __expf(-2.0f * az);           // v_exp_f32
    float r = (1.0f - e) * __builtin_amdgcn_rcpf(1.0f + e);
    return copysignf(r, z);
}

__global__ __launch_bounds__(544)
void rnn_fused_kernel(const float* __restrict__ x,
                      const float* __restrict__ W_ih,
                      const float* __restrict__ W_hh,
                      const float* __restrict__ b_ih,
                      const float* __restrict__ b_hh,
                      const float* __restrict__ W_fc,
                      const float* __restrict__ b_fc,
                      float* __restrict__ out)
{
    __shared__ __align__(16) float xs[TSTEPS * 2];      // 32 KB: x[b,:,:]
    __shared__ __align__(16) float hbuf[2][HPAD];       // double-buffered h

    const int b   = blockIdx.x;
    const int tid = threadIdx.x;
    const int j   = tid >> 2;     // output row this quad owns, 0..135
    const int ks  = tid & 3;      // k-split lane within quad
    const int k0  = ks * KR;      // k-chunk start (0,36,72,108)

    // ---- persistent W_hh row-chunk in registers (zero-padded past H) ----
    float w[KR];
#pragma unroll
    for (int i = 0; i < KR; ++i) {
        int k = k0 + i;
        w[i] = (k < HID) ? W_hh[j * HID + k] : 0.0f;
    }
    float wih0 = W_ih[j * 2 + 0];
    float wih1 = W_ih[j * 2 + 1];
    float bias = b_ih[j] + b_hh[j];

    // ---- stage x[b] into LDS (coalesced float4) ----
    {
        const float4* xg = (const float4*)(x + (size_t)b * TSTEPS * 2);
        float4* xl = (float4*)xs;
        for (int i = tid; i < TSTEPS * 2 / 4; i += 544) xl[i] = xg[i];
    }
    // ---- zero both h buffers (padding stays zero forever) ----
    for (int i = tid; i < 2 * HPAD; i += 544) ((float*)hbuf)[i] = 0.0f;
    __syncthreads();

    // ---- the recurrence ----
    int cur = 0;
    for (int t = 0; t < TSTEPS; ++t) {
        const float4* hp = (const float4*)&hbuf[cur][k0];
        float p0 = 0.f, p1 = 0.f, p2 = 0.f, p3 = 0.f;
#pragma unroll
        for (int i = 0; i < KR / 4; ++i) {          // 9 x ds_read_b128 + 36 FMA
            float4 h4 = hp[i];
            p0 = fmaf(h4.x, w[4 * i + 0], p0);
            p1 = fmaf(h4.y, w[4 * i + 1], p1);
            p2 = fmaf(h4.z, w[4 * i + 2], p2);
            p3 = fmaf(h4.w, w[4 * i + 3], p3);
        }
        float partial = (p0 + p1) + (p2 + p3);
        partial += __shfl_xor(partial, 1);
        partial += __shfl_xor(partial, 2);
        if (ks == 0) {
            float xv0 = xs[t * 2 + 0];
            float xv1 = xs[t * 2 + 1];
            float z = fmaf(xv0, wih0, fmaf(xv1, wih1, bias)) + partial;
            hbuf[cur ^ 1][j] = fast_tanh(z);
        }
        __syncthreads();
        cur ^= 1;
    }

    // ---- final head: out[b][o] = h . W_fc[o,:] + b_fc[o] ----
    const float* h = hbuf[cur];
    if (tid < ODIM * 4) {
        int o = tid >> 2;
        int kend = (k0 + KR < HID) ? (k0 + KR) : HID;
        float p = 0.f;
        for (int k = k0; k < kend; ++k) p = fmaf(h[k], W_fc[o * HID + k], p);
        p += __shfl_xor(p, 1);
        p += __shfl_xor(p, 2);
        if (ks == 0) out[b * ODIM + o] = p + b_fc[o];
    }
}

extern "C" void kernel_launch(void* const* d_in, const int* in_sizes, int n_in,
                              void* d_out, int out_size, void* d_ws, size_t ws_size,
                              hipStream_t stream) {
    const float* x    = (const float*)d_in[0];
    const float* W_ih = (const float*)d_in[1];
    const float* W_hh = (const float*)d_in[2];
    const float* b_ih = (const float*)d_in[3];
    const float* b_hh = (const float*)d_in[4];
    const float* W_fc = (const float*)d_in[5];
    const float* b_fc = (const float*)d_in[6];
    float* out = (float*)d_out;

    rnn_fused_kernel<<<BATCH, 544, 0, stream>>>(x, W_ih, W_hh, b_ih, b_hh,
                                                W_fc, b_fc, out);
}